// Round 1
// baseline (364.580 us; speedup 1.0000x reference)
//
#include <hip/hip_runtime.h>
#include <stdint.h>

// FeatureAttention: N=8192, D=512, U=256, fp32 in/out.
// Q=xWq, K=xWk, V=xWv; out = softmax(QK^T/16) V Wo
// Strategy: bf16 MFMA (16x16x32) everywhere, fp32 accum, flash-style attention
// with KV-split=2 + combine.  All fragment layouts per verified m89/m92/m97:
//   A-frag: lane l holds A[l&15][8*(l>>4)+e]   (8 contiguous k -> ds/global b128)
//   B-frag: lane l holds B[8*(l>>4)+e][l&15]   (contiguous k if B^T row-major)
//   C/D:    reg i  holds C[(l>>4)*4+i][l&15]

#define N_ 8192
#define D_ 512
#define U_ 256

typedef __attribute__((ext_vector_type(8))) short short8;
typedef __attribute__((ext_vector_type(4))) float f32x4;
typedef __attribute__((ext_vector_type(4))) unsigned int u32x4;
typedef __attribute__((ext_vector_type(2))) unsigned int u32x2;

static __device__ __forceinline__ unsigned short f2bf(float f) {
    union { float f; unsigned int u; } c; c.f = f;
    unsigned int u = c.u;
    u += 0x7FFFu + ((u >> 16) & 1u);   // RNE
    return (unsigned short)(u >> 16);
}

// ---------------- kernel 0: weight convert + transpose ----------------
// Wt[j][d]  = W_{q|k|v}[d][j&255]  (j in [0,768): 0-255 q, 256-511 k, 512-767 v)
// Wot[j][u] = W_o[u][j]            (j in [0,512))
__global__ void k_convert(const float* __restrict__ Wq, const float* __restrict__ Wk,
                          const float* __restrict__ Wv, const float* __restrict__ Wo,
                          unsigned short* __restrict__ Wt, unsigned short* __restrict__ Wot) {
    int idx = blockIdx.x * 256 + threadIdx.x;
    const int nWt = 768 * 512;
    if (idx < nWt) {
        int j = idx >> 9, d = idx & 511;
        int which = j >> 8, u = j & 255;
        const float* W = (which == 0) ? Wq : ((which == 1) ? Wk : Wv);
        Wt[idx] = f2bf(W[d * 256 + u]);
    } else {
        int i2 = idx - nWt;
        if (i2 < 512 * 256) {
            int jj = i2 >> 8, u = i2 & 255;
            Wot[i2] = f2bf(Wo[u * 512 + jj]);
        }
    }
}

// ---------------- kernel 1: QKV = x @ [Wq|Wk|Wv] ----------------
// 64x64 tile, 4 waves (16 rows each), K-loop over D=512 in steps of 32.
// A from fp32 x (converted in-register), B from Wt bf16.  V stored transposed.
__global__ __launch_bounds__(256) void k_qkv(const float* __restrict__ x,
        const unsigned short* __restrict__ Wt,
        unsigned short* __restrict__ Q, unsigned short* __restrict__ K,
        unsigned short* __restrict__ Vt) {
    const int w  = threadIdx.x >> 6;
    const int l  = threadIdx.x & 63;
    const int lg = l >> 4, ln = l & 15;
    const int i0 = blockIdx.x * 64 + w * 16;
    const int j0 = blockIdx.y * 64;

    f32x4 acc[4] = {};
#pragma unroll 4
    for (int kc = 0; kc < 16; ++kc) {
        const float* ap = x + (size_t)(i0 + ln) * D_ + kc * 32 + 8 * lg;
        f32x4 a0 = *(const f32x4*)(ap);
        f32x4 a1 = *(const f32x4*)(ap + 4);
        short8 afr;
        afr[0] = (short)f2bf(a0[0]); afr[1] = (short)f2bf(a0[1]);
        afr[2] = (short)f2bf(a0[2]); afr[3] = (short)f2bf(a0[3]);
        afr[4] = (short)f2bf(a1[0]); afr[5] = (short)f2bf(a1[1]);
        afr[6] = (short)f2bf(a1[2]); afr[7] = (short)f2bf(a1[3]);
#pragma unroll
        for (int t = 0; t < 4; ++t) {
            const unsigned short* bp = Wt + (size_t)(j0 + 16 * t + ln) * D_ + kc * 32 + 8 * lg;
            short8 bfr = *(const short8*)bp;
            acc[t] = __builtin_amdgcn_mfma_f32_16x16x32_bf16(afr, bfr, acc[t], 0, 0, 0);
        }
    }
#pragma unroll
    for (int t = 0; t < 4; ++t) {
        int j = j0 + 16 * t + ln;
#pragma unroll
        for (int i = 0; i < 4; ++i) {
            int row = i0 + lg * 4 + i;
            unsigned short v = f2bf(acc[t][i]);
            if (j < 256)        Q[(size_t)row * U_ + j] = v;
            else if (j < 512)   K[(size_t)row * U_ + (j - 256)] = v;
            else                Vt[(size_t)(j - 512) * N_ + row] = v;
        }
    }
}

// ---------------- kernel 2: flash attention partials ----------------
// grid (128, 2): blockIdx.x -> 64 Q rows (4 waves x 16), blockIdx.y -> KV half.
// Per 32-K-row iteration: stage K tile [32][256] and Vt tile [256][32] in LDS
// (XOR-swizzled against bank conflicts), QK^T, online softmax, P through LDS,
// PV accumulate.  Writes unnormalized O + (m,l).
__global__ __launch_bounds__(256) void k_attn(const unsigned short* __restrict__ Q,
        const unsigned short* __restrict__ K, const unsigned short* __restrict__ Vt,
        float* __restrict__ Opart, float* __restrict__ ml) {
    __shared__ __align__(16) char ldsK[16384];   // [32 rows][512 B], byte ^= (row&7)<<4
    __shared__ __align__(16) char ldsV[16384];   // [256 u][64 B],    byte ^= (u&3)<<4
    __shared__ __align__(16) short ldsP[4][16][32];

    const int tid = threadIdx.x;
    const int w = tid >> 6, l = tid & 63, lg = l >> 4, ln = l & 15;
    const int q0 = blockIdx.x * 64 + w * 16;
    const int s  = blockIdx.y;
    const int jbase = s * (N_ / 2);
    const float scale = 0.0625f;

    // Q fragments for this wave's 16 rows (U=256 -> 8 k-chunks)
    short8 qf[8];
#pragma unroll
    for (int kc = 0; kc < 8; ++kc)
        qf[kc] = *(const short8*)(Q + (size_t)(q0 + ln) * U_ + kc * 32 + 8 * lg);

    f32x4 acc[16] = {};
    float mrun[4], lrun[4];
#pragma unroll
    for (int i = 0; i < 4; ++i) { mrun[i] = -3.0e38f; lrun[i] = 0.f; }

    for (int it = 0; it < (N_ / 2) / 32; ++it) {
        const int j0 = jbase + it * 32;
        __syncthreads();
        // ---- stage K tile: global rows j0..j0+31 are contiguous bytes
        {
            const char* gK = (const char*)K + (size_t)j0 * 512;
#pragma unroll
            for (int r = 0; r < 4; ++r) {
                int o = (r * 256 + tid) * 16;
                u32x4 v = *(const u32x4*)(gK + o);
                int row = o >> 9;
                *(u32x4*)(ldsK + (o ^ ((row & 7) << 4))) = v;
            }
            const char* gV = (const char*)Vt + (size_t)j0 * 2;
#pragma unroll
            for (int r = 0; r < 4; ++r) {
                int o = (r * 256 + tid) * 16;
                int u = o >> 6, col = o & 63;
                u32x4 v = *(const u32x4*)(gV + (size_t)u * (N_ * 2) + col);
                *(u32x4*)(ldsV + (o ^ ((u & 3) << 4))) = v;
            }
        }
        __syncthreads();

        // ---- S = (Q K^T): two 16x16 tiles (cols j0..15, j0+16..31)
        f32x4 s0 = {}, s1 = {};
#pragma unroll
        for (int kc = 0; kc < 8; ++kc) {
            int colb = kc * 64 + lg * 16;
            int r0 = ln, r1 = 16 + ln;
            short8 b0 = *(const short8*)(ldsK + r0 * 512 + (colb ^ ((r0 & 7) << 4)));
            short8 b1 = *(const short8*)(ldsK + r1 * 512 + (colb ^ ((r1 & 7) << 4)));
            s0 = __builtin_amdgcn_mfma_f32_16x16x32_bf16(qf[kc], b0, s0, 0, 0, 0);
            s1 = __builtin_amdgcn_mfma_f32_16x16x32_bf16(qf[kc], b1, s1, 0, 0, 0);
        }

        // ---- online softmax (row i lives in reg i, 16 cols across 16-lane group)
        float p0[4], p1[4], alpha[4];
#pragma unroll
        for (int i = 0; i < 4; ++i) {
            float a = s0[i] * scale, b = s1[i] * scale;
            float mx = fmaxf(a, b);
#pragma unroll
            for (int off = 1; off < 16; off <<= 1)
                mx = fmaxf(mx, __shfl_xor(mx, off, 64));
            float mn = fmaxf(mrun[i], mx);
            float al = __expf(mrun[i] - mn);
            float e0 = __expf(a - mn), e1 = __expf(b - mn);
            float rs = e0 + e1;
#pragma unroll
            for (int off = 1; off < 16; off <<= 1)
                rs += __shfl_xor(rs, off, 64);
            lrun[i] = lrun[i] * al + rs;
            mrun[i] = mn;
            alpha[i] = al; p0[i] = e0; p1[i] = e1;
        }
#pragma unroll
        for (int t = 0; t < 16; ++t)
#pragma unroll
            for (int i = 0; i < 4; ++i) acc[t][i] *= alpha[i];

        // ---- P: C-layout -> A-layout via per-wave LDS tile
#pragma unroll
        for (int i = 0; i < 4; ++i) {
            ldsP[w][lg * 4 + i][ln]      = (short)f2bf(p0[i]);
            ldsP[w][lg * 4 + i][16 + ln] = (short)f2bf(p1[i]);
        }
        asm volatile("s_waitcnt lgkmcnt(0)" ::: "memory");
        __builtin_amdgcn_sched_barrier(0);
        short8 pa = *(const short8*)(&ldsP[w][ln][8 * lg]);

        // ---- O += P @ V  (16 u-tiles)
#pragma unroll
        for (int t = 0; t < 16; ++t) {
            int u = t * 16 + ln;
            short8 bv = *(const short8*)(ldsV + u * 64 + ((lg * 16) ^ ((u & 3) << 4)));
            acc[t] = __builtin_amdgcn_mfma_f32_16x16x32_bf16(pa, bv, acc[t], 0, 0, 0);
        }
    }

    // ---- write partials
    float* Op = Opart + (size_t)s * N_ * U_;
#pragma unroll
    for (int t = 0; t < 16; ++t) {
        int u = t * 16 + ln;
#pragma unroll
        for (int i = 0; i < 4; ++i) {
            int row = q0 + lg * 4 + i;
            Op[(size_t)row * U_ + u] = acc[t][i];
        }
    }
    if (ln == 0) {
#pragma unroll
        for (int i = 0; i < 4; ++i) {
            int row = q0 + lg * 4 + i;
            ml[(size_t)s * 2 * N_ + row]      = mrun[i];
            ml[(size_t)s * 2 * N_ + N_ + row] = lrun[i];
        }
    }
}

// ---------------- kernel 3: combine 2 KV-splits -> PV bf16 ----------------
__global__ void k_combine(const float* __restrict__ Opart, const float* __restrict__ ml,
                          unsigned short* __restrict__ PV) {
    int idx = blockIdx.x * 256 + threadIdx.x;      // one thread = 4 u's of one row
    int row = idx >> 6;
    int u4  = (idx & 63) * 4;
    float m0 = ml[row],            l0 = ml[N_ + row];
    float m1 = ml[2 * N_ + row],   l1 = ml[3 * N_ + row];
    float m  = fmaxf(m0, m1);
    float a0 = __expf(m0 - m), a1 = __expf(m1 - m);
    float inv = 1.0f / (l0 * a0 + l1 * a1);
    f32x4 o0 = *(const f32x4*)(Opart + (size_t)row * U_ + u4);
    f32x4 o1 = *(const f32x4*)(Opart + (size_t)N_ * U_ + (size_t)row * U_ + u4);
    unsigned int lo = (unsigned int)f2bf((o0[0] * a0 + o1[0] * a1) * inv)
                    | ((unsigned int)f2bf((o0[1] * a0 + o1[1] * a1) * inv) << 16);
    unsigned int hi = (unsigned int)f2bf((o0[2] * a0 + o1[2] * a1) * inv)
                    | ((unsigned int)f2bf((o0[3] * a0 + o1[3] * a1) * inv) << 16);
    u32x2 pk; pk[0] = lo; pk[1] = hi;
    *(u32x2*)(PV + (size_t)row * U_ + u4) = pk;
}

// ---------------- kernel 4: out = PV @ Wo ----------------
__global__ __launch_bounds__(256) void k_out(const unsigned short* __restrict__ PV,
        const unsigned short* __restrict__ Wot, float* __restrict__ out) {
    const int w = threadIdx.x >> 6, l = threadIdx.x & 63;
    const int lg = l >> 4, ln = l & 15;
    const int i0 = blockIdx.x * 64 + w * 16;
    const int j0 = blockIdx.y * 64;
    f32x4 acc[4] = {};
#pragma unroll
    for (int kc = 0; kc < 8; ++kc) {
        short8 afr = *(const short8*)(PV + (size_t)(i0 + ln) * U_ + kc * 32 + 8 * lg);
#pragma unroll
        for (int t = 0; t < 4; ++t) {
            short8 bfr = *(const short8*)(Wot + (size_t)(j0 + 16 * t + ln) * U_ + kc * 32 + 8 * lg);
            acc[t] = __builtin_amdgcn_mfma_f32_16x16x32_bf16(afr, bfr, acc[t], 0, 0, 0);
        }
    }
#pragma unroll
    for (int t = 0; t < 4; ++t) {
        int j = j0 + 16 * t + ln;
#pragma unroll
        for (int i = 0; i < 4; ++i) {
            int row = i0 + lg * 4 + i;
            out[(size_t)row * D_ + j] = acc[t][i];
        }
    }
}

// ---------------- launch ----------------
extern "C" void kernel_launch(void* const* d_in, const int* in_sizes, int n_in,
                              void* d_out, int out_size, void* d_ws, size_t ws_size,
                              hipStream_t stream) {
    const float* x  = (const float*)d_in[0];
    const float* Wq = (const float*)d_in[1];
    const float* Wk = (const float*)d_in[2];
    const float* Wv = (const float*)d_in[3];
    const float* Wo = (const float*)d_in[4];
    float* out = (float*)d_out;

    char* ws = (char*)d_ws;
    // layout (bytes):
    unsigned short* Wt   = (unsigned short*)(ws);                 //  768*512*2 = 786432
    unsigned short* Wot  = (unsigned short*)(ws + 786432);        //  512*256*2 = 262144
    unsigned short* Q    = (unsigned short*)(ws + 1048576);       // 8192*256*2 = 4 MiB
    unsigned short* K    = (unsigned short*)(ws + 5242880);       // 4 MiB
    unsigned short* Vt   = (unsigned short*)(ws + 9437184);       // 4 MiB (transposed)
    unsigned short* PV   = (unsigned short*)(ws + 13631488);      // 4 MiB
    float*          Opart= (float*)(ws + 17825792);               // 2*8192*256*4 = 16 MiB
    float*          mlp  = (float*)(ws + 34603008);               // 2*2*8192*4
    (void)in_sizes; (void)n_in; (void)out_size; (void)ws_size;

    k_convert<<<2048, 256, 0, stream>>>(Wq, Wk, Wv, Wo, Wt, Wot);
    k_qkv<<<dim3(128, 12), 256, 0, stream>>>(x, Wt, Q, K, Vt);
    k_attn<<<dim3(128, 2), 256, 0, stream>>>(Q, K, Vt, Opart, mlp);
    k_combine<<<2048, 256, 0, stream>>>(Opart, mlp, PV);
    k_out<<<dim3(128, 8), 256, 0, stream>>>(PV, Wot, out);
}